// Round 2
// baseline (767.957 us; speedup 1.0000x reference)
//
#include <hip/hip_runtime.h>
#include <math.h>

// ---- problem constants ----
#define BB 32
#define LL 128
#define HSZ 512
#define PP 12
#define MM 1024
#define VV 50000
#define DD 128
#define CLEN 16
#define NTOT 4096           // B*L

// output offsets (floats)
#define OFF_WORD  0
#define OFF_CHAR  4096
#define OFF_PSR   69632
#define OFF_ATK   593920
#define OFF_OBFM  1118208
#define OFF_CPYM  1122304
#define OFF_PRIM  1126400
#define OFF_CLOSS 1130496
#define OFF_ELOSS 1130497

// ---- exact-ish transcendentals: f32 result via f64 (≈ correctly rounded) ----
__device__ __forceinline__ float EXP32(float x){ return (float)exp((double)x); }
__device__ __forceinline__ float LOG32(float x){ return (float)log((double)x); }

// ---- JAX threefry2x32 (20 rounds) — verified vs known-answer vector ----
__device__ __forceinline__ unsigned rotl32(unsigned x, int r){ return (x<<r)|(x>>(32-r)); }
__device__ __forceinline__ void tf2x32(unsigned k0, unsigned k1, unsigned x0, unsigned x1,
                                       unsigned &o0, unsigned &o1){
  unsigned ks2 = k0 ^ k1 ^ 0x1BD11BDAu;
  x0 += k0; x1 += k1;
  x0+=x1; x1=rotl32(x1,13); x1^=x0;
  x0+=x1; x1=rotl32(x1,15); x1^=x0;
  x0+=x1; x1=rotl32(x1,26); x1^=x0;
  x0+=x1; x1=rotl32(x1, 6); x1^=x0;
  x0+=k1; x1+=ks2+1u;
  x0+=x1; x1=rotl32(x1,17); x1^=x0;
  x0+=x1; x1=rotl32(x1,29); x1^=x0;
  x0+=x1; x1=rotl32(x1,16); x1^=x0;
  x0+=x1; x1=rotl32(x1,24); x1^=x0;
  x0+=ks2; x1+=k0+2u;
  x0+=x1; x1=rotl32(x1,13); x1^=x0;
  x0+=x1; x1=rotl32(x1,15); x1^=x0;
  x0+=x1; x1=rotl32(x1,26); x1^=x0;
  x0+=x1; x1=rotl32(x1, 6); x1^=x0;
  x0+=k0; x1+=k1+3u;
  x0+=x1; x1=rotl32(x1,17); x1^=x0;
  x0+=x1; x1=rotl32(x1,29); x1^=x0;
  x0+=x1; x1=rotl32(x1,16); x1^=x0;
  x0+=x1; x1=rotl32(x1,24); x1^=x0;
  x0+=k1; x1+=ks2+4u;
  x0+=x1; x1=rotl32(x1,13); x1^=x0;
  x0+=x1; x1=rotl32(x1,15); x1^=x0;
  x0+=x1; x1=rotl32(x1,26); x1^=x0;
  x0+=x1; x1=rotl32(x1, 6); x1^=x0;
  x0+=ks2; x1+=k0+5u;
  o0=x0; o1=x1;
}

// jax_threefry_partitionable=True random_bits (bit_width=32):
// per-element count (hi,lo) = (0, e) for e < 2^32; output = o0 ^ o1.
__device__ __forceinline__ unsigned tf_bits32(unsigned k0, unsigned k1, unsigned e){
  unsigned o0, o1; tf2x32(k0, k1, 0u, e, o0, o1); return o0 ^ o1;
}

// jax.random.uniform(key, ..., 1e-6, 1-1e-6) bit manipulation, exact f32 ops
__device__ __forceinline__ float bits_to_unif(unsigned bits){
  const float lo = 1e-6f;
  const float hi = (float)(1.0 - 1e-6);   // fl32(python double 1-1e-6)
  const float span = hi - lo;             // f32 RN fold, mirrors lax.sub
  unsigned fb = (bits >> 9) | 0x3f800000u;
  float f = __fsub_rn(__uint_as_float(fb), 1.0f);
  float r = __fadd_rn(__fmul_rn(f, span), lo);   // mul, add (NOT fused)
  return fmaxf(lo, r);
}

__device__ __forceinline__ float gumbel_from_bits(unsigned bits){
  float u = bits_to_unif(bits);
  float v = -LOG32(u);      // -log(u)
  return -LOG32(v);         // -log(-log(u))
}

__global__ __launch_bounds__(256)
void row_kernel(const float* __restrict__ ctx, const float* __restrict__ dec_W,
                const float* __restrict__ dec_b, const float* __restrict__ psr_w,
                const float* __restrict__ atk_w, const float* __restrict__ cW1,
                const float* __restrict__ cb1, const float* __restrict__ cW2,
                const float* __restrict__ cb2, const int* __restrict__ inp_word,
                const int* __restrict__ inp_pos, const int* __restrict__ inp_mask,
                const int* __restrict__ words, const int* __restrict__ lut,
                float* __restrict__ out, float* __restrict__ ws)
{
  const int n = blockIdx.x;
  const int t = threadIdx.x;

  __shared__ float  ctx_s[HSZ];
  __shared__ float  logit_s[MM];
  __shared__ float  h_s[64];
  __shared__ double redd[256];
  __shared__ float  redf[256];
  __shared__ int    redi[256];
  __shared__ float  sc[2];   // c0, c1 from cpy gumbel
  __shared__ int    si[1];   // argmax idx

  for (int k = t; k < HSZ; k += 256) ctx_s[k] = ctx[(size_t)n*HSZ + k];
  __syncthreads();

  const int  pos   = inp_pos[n];
  const int  word  = inp_word[n];
  const int  msk   = inp_mask[n];
  const bool isobf = (pos < PP);
  const bool ispri = (pos < 4);      // PRI_POS = (0,1,2,3)

  // ---------- cpy MLP: h = relu(ctx@W1+b1) ----------
  if (t < 64){
    double acc = 0.0;
    for (int k = 0; k < HSZ; ++k) acc += (double)ctx_s[k] * (double)cW1[k*64 + t];
    float hv = __fadd_rn((float)acc, cb1[t]);
    h_s[t] = hv > 0.f ? hv : 0.f;
  }
  __syncthreads();

  if (t == 0){
    double a0 = 0.0, a1 = 0.0;
    for (int k = 0; k < 64; ++k){
      double hv = (double)h_s[k];
      a0 += hv * (double)cW2[k*2 + 0];
      a1 += hv * (double)cW2[k*2 + 1];
    }
    float pc0 = __fadd_rn((float)a0, cb2[0]);
    float pc1 = __fadd_rn((float)a1, cb2[1]);
    // pcpy = log_softmax(pc)
    float m2  = fmaxf(pc0, pc1);
    float s0  = __fsub_rn(pc0, m2), s1 = __fsub_rn(pc1, m2);
    float se  = __fadd_rn(EXP32(s0), EXP32(s1));
    float lse = LOG32(se);
    float q0  = __fsub_rn(s0, lse), q1 = __fsub_rn(s1, lse);
    if (ispri){ q0 = 0.0f; q1 = 1.0f; }   // override BEFORE gumbel + logp2

    // gumbel pair, key999 = fold_in(key42, 999); partitionable bits
    unsigned k90, k91; tf2x32(0u, 42u, 0u, 999u, k90, k91);
    float g0 = gumbel_from_bits(tf_bits32(k90, k91, (unsigned)(2*n)));
    float g1 = gumbel_from_bits(tf_bits32(k90, k91, (unsigned)(2*n + 1)));

    // softmax((pcpy+g)/1.0), argmax, straight-through coefficient (1+y)-y
    float x0 = __fadd_rn(q0, g0), x1 = __fadd_rn(q1, g1);
    float mm = fmaxf(x0, x1);
    float ex0 = EXP32(__fsub_rn(x0, mm));
    float ex1 = EXP32(__fsub_rn(x1, mm));
    float ssum = __fadd_rn(ex0, ex1);
    float y0 = __fdiv_rn(ex0, ssum), y1 = __fdiv_rn(ex1, ssum);
    int   idx2 = (y1 > y0) ? 1 : 0;       // jnp.argmax: first index wins ties
    float ysel = idx2 ? y1 : y0;
    float c    = __fsub_rn(__fadd_rn(1.0f, ysel), ysel);  // 1 or 1-2^-24
    sc[0] = (idx2 == 0) ? c : 0.0f;
    sc[1] = (idx2 == 1) ? c : 0.0f;

    // cpy_loss contribution: logp2 = log_softmax(pcpy)[1] on noroot rows
    float m3 = fmaxf(q0, q1);
    float t0 = __fsub_rn(q0, m3), t1 = __fsub_rn(q1, m3);
    float se2 = __fadd_rn(EXP32(t0), EXP32(t1));
    float l21 = __fsub_rn(t1, LOG32(se2));
    if (msk != 0 && (n & (LL-1)) != 0) atomicAdd(ws + 12, l21);
  }

  // ---------- decoder logits + gumbel argmax + entropy (obf rows only) ----------
  if (isobf){
    const float4* W4 = (const float4*)(dec_W + (size_t)pos * HSZ * MM);
    double a0=0.0, a1=0.0, a2=0.0, a3=0.0;
    for (int k = 0; k < HSZ; ++k){
      double c = (double)ctx_s[k];
      float4 w = W4[(size_t)k*256 + t];
      a0 += c*(double)w.x; a1 += c*(double)w.y; a2 += c*(double)w.z; a3 += c*(double)w.w;
    }
    const float* bp = dec_b + (size_t)pos * MM;
    const int m0 = 4*t;
    logit_s[m0+0] = __fadd_rn((float)a0, bp[m0+0]);
    logit_s[m0+1] = __fadd_rn((float)a1, bp[m0+1]);
    logit_s[m0+2] = __fadd_rn((float)a2, bp[m0+2]);
    logit_s[m0+3] = __fadd_rn((float)a3, bp[m0+3]);
    __syncthreads();

    // row max
    float lm = logit_s[m0];
    lm = fmaxf(lm, logit_s[m0+1]); lm = fmaxf(lm, logit_s[m0+2]); lm = fmaxf(lm, logit_s[m0+3]);
    redf[t] = lm; __syncthreads();
    for (int s = 128; s > 0; s >>= 1){ if (t < s) redf[t] = fmaxf(redf[t], redf[t+s]); __syncthreads(); }
    const float xmax = redf[0];
    __syncthreads();

    // sum of f32 exps (accumulated in f64 for order robustness)
    double ds = 0.0;
    for (int j = 0; j < 4; ++j)
      ds += (double)EXP32(__fsub_rn(logit_s[m0+j], xmax));
    redd[t] = ds; __syncthreads();
    for (int s = 128; s > 0; s >>= 1){ if (t < s) redd[t] += redd[t+s]; __syncthreads(); }
    const float lse = LOG32((float)redd[0]);
    __syncthreads();

    // per-p key = fold_in(key42, p)
    unsigned kp0, kp1; tf2x32(0u, 42u, 0u, (unsigned)pos, kp0, kp1);

    float best = -3.4e38f; int bi = 0; double es = 0.0;
    for (int j = 0; j < 4; ++j){
      int m = m0 + j;
      float sh = __fsub_rn(logit_s[m], xmax);
      float lp = __fsub_rn(sh, lse);               // logp
      float ex = EXP32(lp);
      es += (double)__fmul_rn(-lp, ex);            // ent_elem = -logp*exp(logp)
      float g = gumbel_from_bits(tf_bits32(kp0, kp1, (unsigned)(n*MM + m)));
      float sv = __fadd_rn(lp, g);                 // (logp+g)/1.0
      if (sv > best){ best = sv; bi = m; }
    }
    redf[t] = best; redi[t] = bi; redd[t] = es; __syncthreads();
    for (int s = 128; s > 0; s >>= 1){
      if (t < s){
        float v2 = redf[t+s]; int i2 = redi[t+s];
        if (v2 > redf[t] || (v2 == redf[t] && i2 < redi[t])){ redf[t] = v2; redi[t] = i2; }
        redd[t] += redd[t+s];
      }
      __syncthreads();
    }
    if (t == 0){ si[0] = redi[0]; atomicAdd(ws + pos, (float)redd[0]); }
    __syncthreads();
  } else {
    __syncthreads();   // block-uniform branch; make sc[]/si visible
  }

  // ---------- epilogue ----------
  const int   idx = isobf ? si[0] : 0;
  const float c0 = sc[0], c1 = sc[1];
  const int   obf_word = isobf ? words[pos*MM + idx] : word;

  if (t == 0){
    float of = __fadd_rn(__fmul_rn((float)word, c0), __fmul_rn((float)obf_word, c1));
    int ow = (int)of;                                 // astype(int32): trunc toward 0
    out[OFF_WORD + n] = (float)ow;
    bool cpym = (c0 == 1.0f) && (msk != 0);           // exact ==1.0 test, per reference
    out[OFF_CPYM + n] = cpym ? 1.f : 0.f;
    out[OFF_OBFM + n] = (isobf && !cpym) ? 1.f : 0.f;
    out[OFF_PRIM + n] = ispri ? 1.f : 0.f;
    #pragma unroll
    for (int j = 0; j < CLEN; ++j)
      out[OFF_CHAR + (size_t)n*CLEN + j] = (float)lut[(size_t)ow*CLEN + j];
  }
  if (t < DD){
    float po = psr_w[(size_t)word*DD + t];
    float pb = isobf ? psr_w[(size_t)obf_word*DD + t] : po;
    out[OFF_PSR + (size_t)n*DD + t] = __fadd_rn(__fmul_rn(po, c0), __fmul_rn(pb, c1));
    float ao = atk_w[(size_t)word*DD + t];
    float ab = isobf ? atk_w[(size_t)obf_word*DD + t] : ao;
    out[OFF_ATK + (size_t)n*DD + t] = __fadd_rn(__fmul_rn(ao, c0), __fmul_rn(ab, c1));
  }
}

__global__ __launch_bounds__(256)
void fin_kernel(const int* __restrict__ inp_pos, const int* __restrict__ inp_mask,
                const float* __restrict__ ws, float* __restrict__ out)
{
  __shared__ int cnt[PP];
  __shared__ int nr;
  int t = threadIdx.x;
  if (t < PP) cnt[t] = 0;
  if (t == 0) nr = 0;
  __syncthreads();
  int ln = 0;
  for (int n = t; n < NTOT; n += 256){
    int p = inp_pos[n];
    if (p < PP) atomicAdd(&cnt[p], 1);
    if (inp_mask[n] != 0 && (n & (LL-1)) != 0) ln++;
  }
  atomicAdd(&nr, ln);
  __syncthreads();
  if (t == 0){
    float ent = 0.f;
    for (int p = 0; p < PP; ++p){
      int c = cnt[p];
      if (c > 0){
        int denom = c * MM; if (denom < 1) denom = 1;
        ent = __fadd_rn(ent, __fdiv_rn(ws[p], (float)denom));
      }
    }
    out[OFF_ELOSS] = -ent;
    int nrc = nr; if (nrc < 1) nrc = 1;
    out[OFF_CLOSS] = -__fdiv_rn(ws[12], (float)nrc);
  }
}

extern "C" void kernel_launch(void* const* d_in, const int* in_sizes, int n_in,
                              void* d_out, int out_size, void* d_ws, size_t ws_size,
                              hipStream_t stream)
{
  const float* ctx      = (const float*)d_in[0];
  const float* dec_W    = (const float*)d_in[1];
  const float* dec_b    = (const float*)d_in[2];
  const float* psr_w    = (const float*)d_in[3];
  const float* atk_w    = (const float*)d_in[4];
  const float* cW1      = (const float*)d_in[5];
  const float* cb1      = (const float*)d_in[6];
  const float* cW2      = (const float*)d_in[7];
  const float* cb2      = (const float*)d_in[8];
  const int*   inp_word = (const int*)d_in[9];
  const int*   inp_pos  = (const int*)d_in[10];
  const int*   inp_mask = (const int*)d_in[11];
  const int*   words    = (const int*)d_in[12];
  const int*   lut      = (const int*)d_in[13];
  float* out = (float*)d_out;
  float* ws  = (float*)d_ws;

  hipMemsetAsync(ws, 0, 16*sizeof(float), stream);
  row_kernel<<<NTOT, 256, 0, stream>>>(ctx, dec_W, dec_b, psr_w, atk_w,
                                       cW1, cb1, cW2, cb2,
                                       inp_word, inp_pos, inp_mask, words, lut,
                                       out, ws);
  fin_kernel<<<1, 256, 0, stream>>>(inp_pos, inp_mask, ws, out);
}

// Round 3
// 392.187 us; speedup vs baseline: 1.9581x; 1.9581x over previous
//
#include <hip/hip_runtime.h>
#include <math.h>

// ---- problem constants ----
#define BB 32
#define LL 128
#define HSZ 512
#define PP 12
#define MM 1024
#define VV 50000
#define DD 128
#define CLEN 16
#define NTOT 4096           // B*L

// GEMM tiling
#define RT 64               // rows per tile
#define CT 64               // cols per tile
#define BK 64               // k chunk
#define PADW 68             // padded LDS leading dim
#define LISTCAP 512         // max rows per position bucket

// output offsets (floats)
#define OFF_WORD  0
#define OFF_CHAR  4096
#define OFF_PSR   69632
#define OFF_ATK   593920
#define OFF_OBFM  1118208
#define OFF_CPYM  1122304
#define OFF_PRIM  1126400
#define OFF_CLOSS 1130496
#define OFF_ELOSS 1130497

// ws layout (float idx): [0..11] entropy partials, [12] cpy loss,
// int idx [16..27] cnt, int idx [64..6207] rowlist, float idx [8192..] logits
#define WS_LOGITS_OFF 8192

// ---- exact-ish transcendentals: f32 result via f64 (≈ correctly rounded) ----
__device__ __forceinline__ float EXP32(float x){ return (float)exp((double)x); }
__device__ __forceinline__ float LOG32(float x){ return (float)log((double)x); }

// ---- JAX threefry2x32 (20 rounds) — verified vs known-answer vector ----
__device__ __forceinline__ unsigned rotl32(unsigned x, int r){ return (x<<r)|(x>>(32-r)); }
__device__ __forceinline__ void tf2x32(unsigned k0, unsigned k1, unsigned x0, unsigned x1,
                                       unsigned &o0, unsigned &o1){
  unsigned ks2 = k0 ^ k1 ^ 0x1BD11BDAu;
  x0 += k0; x1 += k1;
  x0+=x1; x1=rotl32(x1,13); x1^=x0;
  x0+=x1; x1=rotl32(x1,15); x1^=x0;
  x0+=x1; x1=rotl32(x1,26); x1^=x0;
  x0+=x1; x1=rotl32(x1, 6); x1^=x0;
  x0+=k1; x1+=ks2+1u;
  x0+=x1; x1=rotl32(x1,17); x1^=x0;
  x0+=x1; x1=rotl32(x1,29); x1^=x0;
  x0+=x1; x1=rotl32(x1,16); x1^=x0;
  x0+=x1; x1=rotl32(x1,24); x1^=x0;
  x0+=ks2; x1+=k0+2u;
  x0+=x1; x1=rotl32(x1,13); x1^=x0;
  x0+=x1; x1=rotl32(x1,15); x1^=x0;
  x0+=x1; x1=rotl32(x1,26); x1^=x0;
  x0+=x1; x1=rotl32(x1, 6); x1^=x0;
  x0+=k0; x1+=k1+3u;
  x0+=x1; x1=rotl32(x1,17); x1^=x0;
  x0+=x1; x1=rotl32(x1,29); x1^=x0;
  x0+=x1; x1=rotl32(x1,16); x1^=x0;
  x0+=x1; x1=rotl32(x1,24); x1^=x0;
  x0+=k1; x1+=ks2+4u;
  x0+=x1; x1=rotl32(x1,13); x1^=x0;
  x0+=x1; x1=rotl32(x1,15); x1^=x0;
  x0+=x1; x1=rotl32(x1,26); x1^=x0;
  x0+=x1; x1=rotl32(x1, 6); x1^=x0;
  x0+=ks2; x1+=k0+5u;
  o0=x0; o1=x1;
}

// jax_threefry_partitionable=True random_bits: count (0,e), output o0^o1
__device__ __forceinline__ unsigned tf_bits32(unsigned k0, unsigned k1, unsigned e){
  unsigned o0, o1; tf2x32(k0, k1, 0u, e, o0, o1); return o0 ^ o1;
}

__device__ __forceinline__ float bits_to_unif(unsigned bits){
  const float lo = 1e-6f;
  const float hi = (float)(1.0 - 1e-6);
  const float span = hi - lo;
  unsigned fb = (bits >> 9) | 0x3f800000u;
  float f = __fsub_rn(__uint_as_float(fb), 1.0f);
  float r = __fadd_rn(__fmul_rn(f, span), lo);
  return fmaxf(lo, r);
}

__device__ __forceinline__ float gumbel_from_bits(unsigned bits){
  float u = bits_to_unif(bits);
  float v = -LOG32(u);
  return -LOG32(v);
}

// ---------- Kernel A: bucket rows by position ----------
__global__ __launch_bounds__(256)
void build_idx(const int* __restrict__ inp_pos, int* __restrict__ cntg,
               int* __restrict__ rowlist)
{
  int n = blockIdx.x*256 + threadIdx.x;
  if (n < NTOT){
    int p = inp_pos[n];
    if (p < PP){
      int slot = atomicAdd(&cntg[p], 1);
      if (slot < LISTCAP) rowlist[p*LISTCAP + slot] = n;
    }
  }
}

// ---------- Kernel B: gathered GEMM, f64 acc, same k-order as mono ----------
__global__ __launch_bounds__(256)
void gemm_kernel(const float* __restrict__ ctx, const float* __restrict__ dec_W,
                 const int* __restrict__ cntg, const int* __restrict__ rowlist,
                 float* __restrict__ logits)
{
  const int p  = blockIdx.z;
  const int c0 = blockIdx.x * CT;
  const int r0 = blockIdx.y * RT;
  const int cnt0 = cntg[p];
  const int cnt  = cnt0 < LISTCAP ? cnt0 : LISTCAP;
  if (r0 >= cnt) return;
  const int t = threadIdx.x;

  __shared__ float As[BK][PADW];   // [k][row]
  __shared__ float Bs[BK][PADW];   // [k][col]
  __shared__ int   rid_s[RT];

  if (t < RT){
    int rr = r0 + t;
    rid_s[t] = rowlist[p*LISTCAP + (rr < cnt ? rr : cnt-1)];
  }
  __syncthreads();

  const int tr = t >> 4;        // 0..15 row group (4 rows)
  const int tc = t & 15;        // 0..15 col group (4 cols)

  double acc[4][4];
  #pragma unroll
  for (int i = 0; i < 4; ++i)
    #pragma unroll
    for (int j = 0; j < 4; ++j) acc[i][j] = 0.0;

  const float* Wp = dec_W + (size_t)p * HSZ * MM;

  for (int k0 = 0; k0 < HSZ; k0 += BK){
    // stage A (ctx rows, transposed into [k][row])
    #pragma unroll
    for (int i = 0; i < 4; ++i){
      int idx = t + i*256;          // 0..1023
      int r = idx >> 4;             // 0..63
      int q = idx & 15;             // float4 index within 64 k's
      const float4 v = *(const float4*)(ctx + (size_t)rid_s[r]*HSZ + k0 + q*4);
      As[q*4+0][r] = v.x;
      As[q*4+1][r] = v.y;
      As[q*4+2][r] = v.z;
      As[q*4+3][r] = v.w;
    }
    // stage B (weights [k][col])
    #pragma unroll
    for (int i = 0; i < 4; ++i){
      int idx = t + i*256;
      int kk = idx >> 4;
      int q  = idx & 15;
      const float4 v = *(const float4*)(Wp + (size_t)(k0+kk)*MM + c0 + q*4);
      *(float4*)&Bs[kk][q*4] = v;
    }
    __syncthreads();
    #pragma unroll 4
    for (int kk = 0; kk < BK; ++kk){
      float4 af = *(const float4*)&As[kk][tr*4];
      float4 bf = *(const float4*)&Bs[kk][tc*4];
      double a0 = (double)af.x, a1 = (double)af.y, a2 = (double)af.z, a3 = (double)af.w;
      double b0 = (double)bf.x, b1 = (double)bf.y, b2 = (double)bf.z, b3 = (double)bf.w;
      acc[0][0]+=a0*b0; acc[0][1]+=a0*b1; acc[0][2]+=a0*b2; acc[0][3]+=a0*b3;
      acc[1][0]+=a1*b0; acc[1][1]+=a1*b1; acc[1][2]+=a1*b2; acc[1][3]+=a1*b3;
      acc[2][0]+=a2*b0; acc[2][1]+=a2*b1; acc[2][2]+=a2*b2; acc[2][3]+=a2*b3;
      acc[3][0]+=a3*b0; acc[3][1]+=a3*b1; acc[3][2]+=a3*b2; acc[3][3]+=a3*b3;
    }
    __syncthreads();
  }

  #pragma unroll
  for (int i = 0; i < 4; ++i){
    int rr = r0 + tr*4 + i;
    if (rr < cnt){
      int rg = rid_s[tr*4 + i];
      float4 o;
      o.x = (float)acc[i][0]; o.y = (float)acc[i][1];
      o.z = (float)acc[i][2]; o.w = (float)acc[i][3];
      *(float4*)(logits + (size_t)rg*MM + c0 + tc*4) = o;
    }
  }
}

// ---------- Kernel C: per-row finalize ----------
__global__ __launch_bounds__(256)
void finalize_kernel(const float* __restrict__ ctx, const float* __restrict__ dec_b,
                     const float* __restrict__ psr_w, const float* __restrict__ atk_w,
                     const float* __restrict__ cW1, const float* __restrict__ cb1,
                     const float* __restrict__ cW2, const float* __restrict__ cb2,
                     const int* __restrict__ inp_word, const int* __restrict__ inp_pos,
                     const int* __restrict__ inp_mask, const int* __restrict__ words,
                     const int* __restrict__ lut, const float* __restrict__ logitsbuf,
                     float* __restrict__ out, float* __restrict__ ws)
{
  const int n = blockIdx.x;
  const int t = threadIdx.x;

  __shared__ float  ctx_s[HSZ];
  __shared__ float  logit_s[MM];
  __shared__ float  h_s[64];
  __shared__ double redd[256];
  __shared__ float  redf[256];
  __shared__ int    redi[256];
  __shared__ float  sc[2];
  __shared__ int    si[1];

  for (int k = t; k < HSZ; k += 256) ctx_s[k] = ctx[(size_t)n*HSZ + k];
  __syncthreads();

  const int  pos   = inp_pos[n];
  const int  word  = inp_word[n];
  const int  msk   = inp_mask[n];
  const bool isobf = (pos < PP);
  const bool ispri = (pos < 4);

  // ---------- cpy MLP ----------
  if (t < 64){
    double acc = 0.0;
    for (int k = 0; k < HSZ; ++k) acc += (double)ctx_s[k] * (double)cW1[k*64 + t];
    float hv = __fadd_rn((float)acc, cb1[t]);
    h_s[t] = hv > 0.f ? hv : 0.f;
  }
  __syncthreads();

  if (t == 0){
    double a0 = 0.0, a1 = 0.0;
    for (int k = 0; k < 64; ++k){
      double hv = (double)h_s[k];
      a0 += hv * (double)cW2[k*2 + 0];
      a1 += hv * (double)cW2[k*2 + 1];
    }
    float pc0 = __fadd_rn((float)a0, cb2[0]);
    float pc1 = __fadd_rn((float)a1, cb2[1]);
    float m2  = fmaxf(pc0, pc1);
    float s0  = __fsub_rn(pc0, m2), s1 = __fsub_rn(pc1, m2);
    float se  = __fadd_rn(EXP32(s0), EXP32(s1));
    float lse = LOG32(se);
    float q0  = __fsub_rn(s0, lse), q1 = __fsub_rn(s1, lse);
    if (ispri){ q0 = 0.0f; q1 = 1.0f; }

    unsigned k90, k91; tf2x32(0u, 42u, 0u, 999u, k90, k91);
    float g0 = gumbel_from_bits(tf_bits32(k90, k91, (unsigned)(2*n)));
    float g1 = gumbel_from_bits(tf_bits32(k90, k91, (unsigned)(2*n + 1)));

    float x0 = __fadd_rn(q0, g0), x1 = __fadd_rn(q1, g1);
    float mm = fmaxf(x0, x1);
    float ex0 = EXP32(__fsub_rn(x0, mm));
    float ex1 = EXP32(__fsub_rn(x1, mm));
    float ssum = __fadd_rn(ex0, ex1);
    float y0 = __fdiv_rn(ex0, ssum), y1 = __fdiv_rn(ex1, ssum);
    int   idx2 = (y1 > y0) ? 1 : 0;
    float ysel = idx2 ? y1 : y0;
    float c    = __fsub_rn(__fadd_rn(1.0f, ysel), ysel);
    sc[0] = (idx2 == 0) ? c : 0.0f;
    sc[1] = (idx2 == 1) ? c : 0.0f;

    float m3 = fmaxf(q0, q1);
    float t0 = __fsub_rn(q0, m3), t1 = __fsub_rn(q1, m3);
    float se2 = __fadd_rn(EXP32(t0), EXP32(t1));
    float l21 = __fsub_rn(t1, LOG32(se2));
    if (msk != 0 && (n & (LL-1)) != 0) atomicAdd(ws + 12, l21);
  }

  // ---------- softmax/gumbel/argmax/entropy from precomputed logits ----------
  if (isobf){
    const int m0 = 4*t;
    const float4 lg = *(const float4*)(logitsbuf + (size_t)n*MM + m0);
    const float* bp = dec_b + (size_t)pos * MM;
    logit_s[m0+0] = __fadd_rn(lg.x, bp[m0+0]);
    logit_s[m0+1] = __fadd_rn(lg.y, bp[m0+1]);
    logit_s[m0+2] = __fadd_rn(lg.z, bp[m0+2]);
    logit_s[m0+3] = __fadd_rn(lg.w, bp[m0+3]);
    __syncthreads();

    float lm = logit_s[m0];
    lm = fmaxf(lm, logit_s[m0+1]); lm = fmaxf(lm, logit_s[m0+2]); lm = fmaxf(lm, logit_s[m0+3]);
    redf[t] = lm; __syncthreads();
    for (int s = 128; s > 0; s >>= 1){ if (t < s) redf[t] = fmaxf(redf[t], redf[t+s]); __syncthreads(); }
    const float xmax = redf[0];
    __syncthreads();

    double ds = 0.0;
    for (int j = 0; j < 4; ++j)
      ds += (double)EXP32(__fsub_rn(logit_s[m0+j], xmax));
    redd[t] = ds; __syncthreads();
    for (int s = 128; s > 0; s >>= 1){ if (t < s) redd[t] += redd[t+s]; __syncthreads(); }
    const float lse = LOG32((float)redd[0]);
    __syncthreads();

    unsigned kp0, kp1; tf2x32(0u, 42u, 0u, (unsigned)pos, kp0, kp1);

    float best = -3.4e38f; int bi = 0; double es = 0.0;
    for (int j = 0; j < 4; ++j){
      int m = m0 + j;
      float sh = __fsub_rn(logit_s[m], xmax);
      float lp = __fsub_rn(sh, lse);
      float ex = EXP32(lp);
      es += (double)__fmul_rn(-lp, ex);
      float g = gumbel_from_bits(tf_bits32(kp0, kp1, (unsigned)(n*MM + m)));
      float sv = __fadd_rn(lp, g);
      if (sv > best){ best = sv; bi = m; }
    }
    redf[t] = best; redi[t] = bi; redd[t] = es; __syncthreads();
    for (int s = 128; s > 0; s >>= 1){
      if (t < s){
        float v2 = redf[t+s]; int i2 = redi[t+s];
        if (v2 > redf[t] || (v2 == redf[t] && i2 < redi[t])){ redf[t] = v2; redi[t] = i2; }
        redd[t] += redd[t+s];
      }
      __syncthreads();
    }
    if (t == 0){ si[0] = redi[0]; atomicAdd(ws + pos, (float)redd[0]); }
    __syncthreads();
  } else {
    __syncthreads();
  }

  // ---------- epilogue ----------
  const int   idx = isobf ? si[0] : 0;
  const float c0 = sc[0], c1 = sc[1];
  const int   obf_word = isobf ? words[pos*MM + idx] : word;

  if (t == 0){
    float of = __fadd_rn(__fmul_rn((float)word, c0), __fmul_rn((float)obf_word, c1));
    int ow = (int)of;
    out[OFF_WORD + n] = (float)ow;
    bool cpym = (c0 == 1.0f) && (msk != 0);
    out[OFF_CPYM + n] = cpym ? 1.f : 0.f;
    out[OFF_OBFM + n] = (isobf && !cpym) ? 1.f : 0.f;
    out[OFF_PRIM + n] = ispri ? 1.f : 0.f;
    #pragma unroll
    for (int j = 0; j < CLEN; ++j)
      out[OFF_CHAR + (size_t)n*CLEN + j] = (float)lut[(size_t)ow*CLEN + j];
  }
  if (t < DD){
    float po = psr_w[(size_t)word*DD + t];
    float pb = isobf ? psr_w[(size_t)obf_word*DD + t] : po;
    out[OFF_PSR + (size_t)n*DD + t] = __fadd_rn(__fmul_rn(po, c0), __fmul_rn(pb, c1));
    float ao = atk_w[(size_t)word*DD + t];
    float ab = isobf ? atk_w[(size_t)obf_word*DD + t] : ao;
    out[OFF_ATK + (size_t)n*DD + t] = __fadd_rn(__fmul_rn(ao, c0), __fmul_rn(ab, c1));
  }
}

// ---------- monolithic fallback (round-2 kernel) if ws is too small ----------
__global__ __launch_bounds__(256)
void row_kernel_mono(const float* __restrict__ ctx, const float* __restrict__ dec_W,
                const float* __restrict__ dec_b, const float* __restrict__ psr_w,
                const float* __restrict__ atk_w, const float* __restrict__ cW1,
                const float* __restrict__ cb1, const float* __restrict__ cW2,
                const float* __restrict__ cb2, const int* __restrict__ inp_word,
                const int* __restrict__ inp_pos, const int* __restrict__ inp_mask,
                const int* __restrict__ words, const int* __restrict__ lut,
                float* __restrict__ out, float* __restrict__ ws)
{
  const int n = blockIdx.x;
  const int t = threadIdx.x;

  __shared__ float  ctx_s[HSZ];
  __shared__ float  logit_s[MM];
  __shared__ float  h_s[64];
  __shared__ double redd[256];
  __shared__ float  redf[256];
  __shared__ int    redi[256];
  __shared__ float  sc[2];
  __shared__ int    si[1];

  for (int k = t; k < HSZ; k += 256) ctx_s[k] = ctx[(size_t)n*HSZ + k];
  __syncthreads();

  const int  pos   = inp_pos[n];
  const int  word  = inp_word[n];
  const int  msk   = inp_mask[n];
  const bool isobf = (pos < PP);
  const bool ispri = (pos < 4);

  if (t < 64){
    double acc = 0.0;
    for (int k = 0; k < HSZ; ++k) acc += (double)ctx_s[k] * (double)cW1[k*64 + t];
    float hv = __fadd_rn((float)acc, cb1[t]);
    h_s[t] = hv > 0.f ? hv : 0.f;
  }
  __syncthreads();

  if (t == 0){
    double a0 = 0.0, a1 = 0.0;
    for (int k = 0; k < 64; ++k){
      double hv = (double)h_s[k];
      a0 += hv * (double)cW2[k*2 + 0];
      a1 += hv * (double)cW2[k*2 + 1];
    }
    float pc0 = __fadd_rn((float)a0, cb2[0]);
    float pc1 = __fadd_rn((float)a1, cb2[1]);
    float m2  = fmaxf(pc0, pc1);
    float s0  = __fsub_rn(pc0, m2), s1 = __fsub_rn(pc1, m2);
    float se  = __fadd_rn(EXP32(s0), EXP32(s1));
    float lse = LOG32(se);
    float q0  = __fsub_rn(s0, lse), q1 = __fsub_rn(s1, lse);
    if (ispri){ q0 = 0.0f; q1 = 1.0f; }

    unsigned k90, k91; tf2x32(0u, 42u, 0u, 999u, k90, k91);
    float g0 = gumbel_from_bits(tf_bits32(k90, k91, (unsigned)(2*n)));
    float g1 = gumbel_from_bits(tf_bits32(k90, k91, (unsigned)(2*n + 1)));

    float x0 = __fadd_rn(q0, g0), x1 = __fadd_rn(q1, g1);
    float mm = fmaxf(x0, x1);
    float ex0 = EXP32(__fsub_rn(x0, mm));
    float ex1 = EXP32(__fsub_rn(x1, mm));
    float ssum = __fadd_rn(ex0, ex1);
    float y0 = __fdiv_rn(ex0, ssum), y1 = __fdiv_rn(ex1, ssum);
    int   idx2 = (y1 > y0) ? 1 : 0;
    float ysel = idx2 ? y1 : y0;
    float c    = __fsub_rn(__fadd_rn(1.0f, ysel), ysel);
    sc[0] = (idx2 == 0) ? c : 0.0f;
    sc[1] = (idx2 == 1) ? c : 0.0f;

    float m3 = fmaxf(q0, q1);
    float t0 = __fsub_rn(q0, m3), t1 = __fsub_rn(q1, m3);
    float se2 = __fadd_rn(EXP32(t0), EXP32(t1));
    float l21 = __fsub_rn(t1, LOG32(se2));
    if (msk != 0 && (n & (LL-1)) != 0) atomicAdd(ws + 12, l21);
  }

  if (isobf){
    const float4* W4 = (const float4*)(dec_W + (size_t)pos * HSZ * MM);
    double a0=0.0, a1=0.0, a2=0.0, a3=0.0;
    for (int k = 0; k < HSZ; ++k){
      double c = (double)ctx_s[k];
      float4 w = W4[(size_t)k*256 + t];
      a0 += c*(double)w.x; a1 += c*(double)w.y; a2 += c*(double)w.z; a3 += c*(double)w.w;
    }
    const float* bp = dec_b + (size_t)pos * MM;
    const int m0 = 4*t;
    logit_s[m0+0] = __fadd_rn((float)a0, bp[m0+0]);
    logit_s[m0+1] = __fadd_rn((float)a1, bp[m0+1]);
    logit_s[m0+2] = __fadd_rn((float)a2, bp[m0+2]);
    logit_s[m0+3] = __fadd_rn((float)a3, bp[m0+3]);
    __syncthreads();

    float lm = logit_s[m0];
    lm = fmaxf(lm, logit_s[m0+1]); lm = fmaxf(lm, logit_s[m0+2]); lm = fmaxf(lm, logit_s[m0+3]);
    redf[t] = lm; __syncthreads();
    for (int s = 128; s > 0; s >>= 1){ if (t < s) redf[t] = fmaxf(redf[t], redf[t+s]); __syncthreads(); }
    const float xmax = redf[0];
    __syncthreads();

    double ds = 0.0;
    for (int j = 0; j < 4; ++j)
      ds += (double)EXP32(__fsub_rn(logit_s[m0+j], xmax));
    redd[t] = ds; __syncthreads();
    for (int s = 128; s > 0; s >>= 1){ if (t < s) redd[t] += redd[t+s]; __syncthreads(); }
    const float lse = LOG32((float)redd[0]);
    __syncthreads();

    unsigned kp0, kp1; tf2x32(0u, 42u, 0u, (unsigned)pos, kp0, kp1);

    float best = -3.4e38f; int bi = 0; double es = 0.0;
    for (int j = 0; j < 4; ++j){
      int m = m0 + j;
      float sh = __fsub_rn(logit_s[m], xmax);
      float lp = __fsub_rn(sh, lse);
      float ex = EXP32(lp);
      es += (double)__fmul_rn(-lp, ex);
      float g = gumbel_from_bits(tf_bits32(kp0, kp1, (unsigned)(n*MM + m)));
      float sv = __fadd_rn(lp, g);
      if (sv > best){ best = sv; bi = m; }
    }
    redf[t] = best; redi[t] = bi; redd[t] = es; __syncthreads();
    for (int s = 128; s > 0; s >>= 1){
      if (t < s){
        float v2 = redf[t+s]; int i2 = redi[t+s];
        if (v2 > redf[t] || (v2 == redf[t] && i2 < redi[t])){ redf[t] = v2; redi[t] = i2; }
        redd[t] += redd[t+s];
      }
      __syncthreads();
    }
    if (t == 0){ si[0] = redi[0]; atomicAdd(ws + pos, (float)redd[0]); }
    __syncthreads();
  } else {
    __syncthreads();
  }

  const int   idx = isobf ? si[0] : 0;
  const float c0 = sc[0], c1 = sc[1];
  const int   obf_word = isobf ? words[pos*MM + idx] : word;

  if (t == 0){
    float of = __fadd_rn(__fmul_rn((float)word, c0), __fmul_rn((float)obf_word, c1));
    int ow = (int)of;
    out[OFF_WORD + n] = (float)ow;
    bool cpym = (c0 == 1.0f) && (msk != 0);
    out[OFF_CPYM + n] = cpym ? 1.f : 0.f;
    out[OFF_OBFM + n] = (isobf && !cpym) ? 1.f : 0.f;
    out[OFF_PRIM + n] = ispri ? 1.f : 0.f;
    #pragma unroll
    for (int j = 0; j < CLEN; ++j)
      out[OFF_CHAR + (size_t)n*CLEN + j] = (float)lut[(size_t)ow*CLEN + j];
  }
  if (t < DD){
    float po = psr_w[(size_t)word*DD + t];
    float pb = isobf ? psr_w[(size_t)obf_word*DD + t] : po;
    out[OFF_PSR + (size_t)n*DD + t] = __fadd_rn(__fmul_rn(po, c0), __fmul_rn(pb, c1));
    float ao = atk_w[(size_t)word*DD + t];
    float ab = isobf ? atk_w[(size_t)obf_word*DD + t] : ao;
    out[OFF_ATK + (size_t)n*DD + t] = __fadd_rn(__fmul_rn(ao, c0), __fmul_rn(ab, c1));
  }
}

__global__ __launch_bounds__(256)
void fin_kernel(const int* __restrict__ inp_pos, const int* __restrict__ inp_mask,
                const float* __restrict__ ws, float* __restrict__ out)
{
  __shared__ int cnt[PP];
  __shared__ int nr;
  int t = threadIdx.x;
  if (t < PP) cnt[t] = 0;
  if (t == 0) nr = 0;
  __syncthreads();
  int ln = 0;
  for (int n = t; n < NTOT; n += 256){
    int p = inp_pos[n];
    if (p < PP) atomicAdd(&cnt[p], 1);
    if (inp_mask[n] != 0 && (n & (LL-1)) != 0) ln++;
  }
  atomicAdd(&nr, ln);
  __syncthreads();
  if (t == 0){
    float ent = 0.f;
    for (int p = 0; p < PP; ++p){
      int c = cnt[p];
      if (c > 0){
        int denom = c * MM; if (denom < 1) denom = 1;
        ent = __fadd_rn(ent, __fdiv_rn(ws[p], (float)denom));
      }
    }
    out[OFF_ELOSS] = -ent;
    int nrc = nr; if (nrc < 1) nrc = 1;
    out[OFF_CLOSS] = -__fdiv_rn(ws[12], (float)nrc);
  }
}

extern "C" void kernel_launch(void* const* d_in, const int* in_sizes, int n_in,
                              void* d_out, int out_size, void* d_ws, size_t ws_size,
                              hipStream_t stream)
{
  const float* ctx      = (const float*)d_in[0];
  const float* dec_W    = (const float*)d_in[1];
  const float* dec_b    = (const float*)d_in[2];
  const float* psr_w    = (const float*)d_in[3];
  const float* atk_w    = (const float*)d_in[4];
  const float* cW1      = (const float*)d_in[5];
  const float* cb1      = (const float*)d_in[6];
  const float* cW2      = (const float*)d_in[7];
  const float* cb2      = (const float*)d_in[8];
  const int*   inp_word = (const int*)d_in[9];
  const int*   inp_pos  = (const int*)d_in[10];
  const int*   inp_mask = (const int*)d_in[11];
  const int*   words    = (const int*)d_in[12];
  const int*   lut      = (const int*)d_in[13];
  float* out = (float*)d_out;
  float* ws  = (float*)d_ws;

  const size_t need = (size_t)WS_LOGITS_OFF*4 + (size_t)NTOT*MM*4;

  hipMemsetAsync(ws, 0, 512, stream);   // zero loss partials + counters

  if (ws_size >= need){
    int*   cntg      = (int*)ws + 16;
    int*   rowlist   = (int*)ws + 64;
    float* logitsbuf = ws + WS_LOGITS_OFF;
    build_idx<<<NTOT/256, 256, 0, stream>>>(inp_pos, cntg, rowlist);
    gemm_kernel<<<dim3(MM/CT, LISTCAP/RT, PP), 256, 0, stream>>>(ctx, dec_W, cntg, rowlist, logitsbuf);
    finalize_kernel<<<NTOT, 256, 0, stream>>>(ctx, dec_b, psr_w, atk_w,
                                              cW1, cb1, cW2, cb2,
                                              inp_word, inp_pos, inp_mask, words, lut,
                                              logitsbuf, out, ws);
  } else {
    row_kernel_mono<<<NTOT, 256, 0, stream>>>(ctx, dec_W, dec_b, psr_w, atk_w,
                                              cW1, cb1, cW2, cb2,
                                              inp_word, inp_pos, inp_mask, words, lut,
                                              out, ws);
  }
  fin_kernel<<<1, 256, 0, stream>>>(inp_pos, inp_mask, ws, out);
}